// Round 16
// baseline (200.571 us; speedup 1.0000x reference)
//
#include <hip/hip_runtime.h>
#include <stdint.h>

// ============================================================================
// MultiHeadAttentionFast: x[2,4096,1024] -> QKV gemm -> causal MHA -> proj
// B=2 S=4096 D=1024 H=16 DK=DV=64, QKV_OUT=3072. fp32 in/out, bf16 MFMA core.
// R16: attn — lsum computed on the MFMA pipe via ones-column trick:
//      lacc[m] = mfma(pa[m], ones) accumulates row sums of P in exactly
//      oacc's row layout (no epilogue shuffles). Removes 32 VALU adds/iter
//      (VALU was the binding pipe: 62% vs MFMA 35%). Rest identical to R15.
// Workspace layout (bytes):
//   xb @0 (16MB) | WqkvT @16777216 (6MB) | WprojT @23068672 (2MB)
//   Q @25165824 | K @41943040 | V^T @58720256 | O @75497472 (16MB each)
// ============================================================================

typedef __bf16 bf16x8 __attribute__((ext_vector_type(8)));
typedef float f32x4 __attribute__((ext_vector_type(4)));
typedef unsigned short u16x8 __attribute__((ext_vector_type(8)));
typedef unsigned short u16x4 __attribute__((ext_vector_type(4)));
typedef unsigned int u32x4 __attribute__((ext_vector_type(4)));

__device__ __forceinline__ unsigned short f2bf(float f) {
  unsigned u = __builtin_bit_cast(unsigned, f);
  u += 0x7FFFu + ((u >> 16) & 1u);   // RNE
  return (unsigned short)(u >> 16);
}

__device__ __forceinline__ float fast_exp2(float x) {
#if __has_builtin(__builtin_amdgcn_exp2f)
  return __builtin_amdgcn_exp2f(x);
#else
  return exp2f(x);
#endif
}

// global -> LDS direct, 16B per lane (wave-uniform LDS base + lane*16).
__device__ __forceinline__ void gload16(const void* g, void* l) {
  __builtin_amdgcn_global_load_lds(
      (__attribute__((address_space(1))) unsigned int*)(uintptr_t)g,
      (__attribute__((address_space(3))) unsigned int*)(unsigned int)(uintptr_t)l,
      16, 0, 0);
}

// ---------------------------------------------------------------------------
__global__ void k_cvt_bf16(const float* __restrict__ in,
                           unsigned short* __restrict__ out, int n8) {
  int i = blockIdx.x * blockDim.x + threadIdx.x;
  if (i >= n8) return;
  const float4* p = reinterpret_cast<const float4*>(in) + (size_t)i * 2;
  float4 a = p[0], b = p[1];
  u16x8 o;
  o[0] = f2bf(a.x); o[1] = f2bf(a.y); o[2] = f2bf(a.z); o[3] = f2bf(a.w);
  o[4] = f2bf(b.x); o[5] = f2bf(b.y); o[6] = f2bf(b.z); o[7] = f2bf(b.w);
  *(reinterpret_cast<u16x8*>(out) + i) = o;
}

__global__ void k_transcvt(const float* __restrict__ in,
                           unsigned short* __restrict__ out, int K, int N) {
  __shared__ float tile[32][33];
  int tk0 = blockIdx.y << 5, tn0 = blockIdx.x << 5;
  int t = threadIdx.x;
  int r = t >> 3, c4 = (t & 7) << 2;
  float4 v = *reinterpret_cast<const float4*>(&in[(size_t)(tk0 + r) * N + tn0 + c4]);
  tile[r][c4 + 0] = v.x; tile[r][c4 + 1] = v.y;
  tile[r][c4 + 2] = v.z; tile[r][c4 + 3] = v.w;
  __syncthreads();
  u16x4 o;
  o[0] = f2bf(tile[c4 + 0][r]); o[1] = f2bf(tile[c4 + 1][r]);
  o[2] = f2bf(tile[c4 + 2][r]); o[3] = f2bf(tile[c4 + 3][r]);
  *reinterpret_cast<u16x4*>(&out[(size_t)(tn0 + r) * K + tk0 + c4]) = o;
}

// ---------------------------------------------------------------------------
// Double-buffered 128x128x(K=1024) bf16 GEMM core, BK=32, 4 waves (2x2).
// Per iter: prefetch next K-tile into buf^1 (8 gload16), 8 ds_read_b128,
// 16 MFMA, vmcnt(0) (drain hidden under compute), ONE barrier. (R13, best.)
__device__ __forceinline__ void gemm_core_db(
    const unsigned short* __restrict__ A, const unsigned short* __restrict__ Bt,
    unsigned short (*Al)[128 * 32], unsigned short (*Bl)[128 * 32],
    int m0, int n0, f32x4 acc[4][4]) {
  const int t = threadIdx.x;
  const int lane = t & 63;
  const int w = t >> 6;
  const int wr = w >> 1, wc = w & 1;
  const int l15 = lane & 15, l4 = lane >> 4;

  const int c0 = t, c1 = t + 256;
  const int r0 = c0 >> 2, s0 = ((c0 & 3) << 3) ^ (((r0 >> 1) & 3) << 3);
  const int r1 = c1 >> 2, s1 = ((c1 & 3) << 3) ^ (((r1 >> 1) & 3) << 3);
  const size_t ga0 = (size_t)(m0 + r0) * 1024 + s0;
  const size_t ga1 = (size_t)(m0 + r1) * 1024 + s1;
  const size_t gb0 = (size_t)(n0 + r0) * 1024 + s0;
  const size_t gb1 = (size_t)(n0 + r1) * 1024 + s1;

  int aidx[4], bidx[4];
#pragma unroll
  for (int m = 0; m < 4; ++m) {
    int row = wr * 64 + m * 16 + l15;
    aidx[m] = row * 32 + ((l4 * 8) ^ (((row >> 1) & 3) << 3));
    row = wc * 64 + m * 16 + l15;
    bidx[m] = row * 32 + ((l4 * 8) ^ (((row >> 1) & 3) << 3));
  }

#define GSTAGE(bufi, kofs)                                   \
  do {                                                       \
    gload16(A + ga0 + (kofs), Al[bufi] + c0 * 8);            \
    gload16(A + ga1 + (kofs), Al[bufi] + c1 * 8);            \
    gload16(Bt + gb0 + (kofs), Bl[bufi] + c0 * 8);           \
    gload16(Bt + gb1 + (kofs), Bl[bufi] + c1 * 8);           \
  } while (0)

  GSTAGE(0, 0);
  asm volatile("s_waitcnt vmcnt(0)" ::: "memory");
  __builtin_amdgcn_s_barrier();

#pragma unroll 1
  for (int it = 0; it < 32; ++it) {
    const int cur = it & 1;
    if (it + 1 < 32) GSTAGE(cur ^ 1, (it + 1) * 32);  // prefetch flies
    bf16x8 af[4], bfr[4];
#pragma unroll
    for (int m = 0; m < 4; ++m)
      af[m] = *reinterpret_cast<const bf16x8*>(Al[cur] + aidx[m]);
#pragma unroll
    for (int n = 0; n < 4; ++n)
      bfr[n] = *reinterpret_cast<const bf16x8*>(Bl[cur] + bidx[n]);
    __builtin_amdgcn_s_setprio(1);
#pragma unroll
    for (int m = 0; m < 4; ++m)
#pragma unroll
      for (int n = 0; n < 4; ++n)
        acc[m][n] = __builtin_amdgcn_mfma_f32_16x16x32_bf16(af[m], bfr[n],
                                                            acc[m][n], 0, 0, 0);
    __builtin_amdgcn_s_setprio(0);
    asm volatile("s_waitcnt vmcnt(0)" ::: "memory");  // own prefetch landed
    __builtin_amdgcn_s_barrier();                     // all waves: buf ready
  }
#undef GSTAGE
}

__global__ __launch_bounds__(256) void k_gemm_qkv(
    const unsigned short* __restrict__ A, const unsigned short* __restrict__ Bt,
    const float* __restrict__ bias, unsigned short* __restrict__ Qb,
    unsigned short* __restrict__ Kb, unsigned short* __restrict__ VTb) {
  __shared__ unsigned short Al[2][128 * 32];
  __shared__ unsigned short Bl[2][128 * 32];
  const int lane = threadIdx.x & 63, w = threadIdx.x >> 6;
  const int wr = w >> 1, wc = w & 1;
  const int l15 = lane & 15, l4 = lane >> 4;
  const int m0 = blockIdx.y << 7, n0 = blockIdx.x << 7;
  const float C1 = 0.18033688011112043f;   // 0.125 * log2(e), folded into Q

  f32x4 acc[4][4] = {};
  gemm_core_db(A, Bt, Al, Bl, m0, n0, acc);

  float bi[4];
#pragma unroll
  for (int n = 0; n < 4; ++n) bi[n] = bias[n0 + wc * 64 + n * 16 + l15];

  if (n0 < 2048) {          // Q or K region: coalesced 2B stores (d-contig)
#pragma unroll
    for (int m = 0; m < 4; ++m)
#pragma unroll
      for (int n = 0; n < 4; ++n)
#pragma unroll
        for (int j = 0; j < 4; ++j) {
          int row = m0 + wr * 64 + m * 16 + l4 * 4 + j;
          int col = n0 + wc * 64 + n * 16 + l15;
          float v = acc[m][n][j] + bi[n];
          int b = row >> 12, s = row & 4095;
          if (col < 1024) {
            int hh = col >> 6, d = col & 63;
            Qb[((size_t)(b * 16 + hh) * 4096 + s) * 64 + d] = f2bf(v * C1);
          } else {
            int cc = col - 1024; int hh = cc >> 6, d = cc & 63;
            Kb[((size_t)(b * 16 + hh) * 4096 + s) * 64 + d] = f2bf(v);
          }
        }
  } else {                  // V region -> V^T: 4 consecutive s, packed 8B
#pragma unroll
    for (int m = 0; m < 4; ++m)
#pragma unroll
      for (int n = 0; n < 4; ++n) {
        int row0 = m0 + wr * 64 + m * 16 + l4 * 4;
        int cc = n0 - 2048 + wc * 64 + n * 16 + l15;
        int b = row0 >> 12, s0 = row0 & 4095;
        int hh = cc >> 6, d = cc & 63;
        u16x4 pk;
#pragma unroll
        for (int j = 0; j < 4; ++j) pk[j] = f2bf(acc[m][n][j] + bi[n]);
        *reinterpret_cast<u16x4*>(
            &VTb[((size_t)(b * 16 + hh) * 64 + d) * 4096 + s0]) = pk;
      }
  }
}

__global__ __launch_bounds__(256) void k_gemm_proj(
    const unsigned short* __restrict__ A, const unsigned short* __restrict__ Bt,
    const float* __restrict__ bias, float* __restrict__ out) {
  __shared__ unsigned short Al[2][128 * 32];
  __shared__ unsigned short Bl[2][128 * 32];
  const int lane = threadIdx.x & 63, w = threadIdx.x >> 6;
  const int wr = w >> 1, wc = w & 1;
  const int l15 = lane & 15, l4 = lane >> 4;
  const int m0 = blockIdx.y << 7, n0 = blockIdx.x << 7;

  f32x4 acc[4][4] = {};
  gemm_core_db(A, Bt, Al, Bl, m0, n0, acc);

#pragma unroll
  for (int m = 0; m < 4; ++m) {
#pragma unroll
    for (int n = 0; n < 4; ++n) {
#pragma unroll
      for (int j = 0; j < 4; ++j) {
        int row = m0 + wr * 64 + m * 16 + l4 * 4 + j;
        int col = n0 + wc * 64 + n * 16 + l15;
        out[(size_t)row * 1024 + col] = acc[m][n][j] + bias[col];
      }
    }
  }
}

// ---------------------------------------------------------------------------
// Flash attention R16. 1024 blocks (balanced qt bijection), 4 waves x 32
// q-rows. Swapped QK^T (Q pre-scaled); P in registers via cvt_pk + permlane;
// row sums via ones-column MFMA: lacc[m] = mfma(pa[m], ones) — lands in
// oacc's row layout, epilogue shuffle-free.
__global__ __launch_bounds__(256, 4) void k_attn(
    const unsigned short* __restrict__ Qb, const unsigned short* __restrict__ Kb,
    const unsigned short* __restrict__ VTb, unsigned short* __restrict__ Ob) {
  __shared__ unsigned short Kl[2][64 * 64];
  __shared__ unsigned short Vl[2][64 * 64];
  const int t = threadIdx.x;
  const int lane = t & 63, w = t >> 6;
  const int l15 = lane & 15, l4 = lane >> 4;
  const int idx = blockIdx.x;
  const int r = idx >> 8;                     // round 0..3
  const int g = (idx >> 5) & 7;               // group 0..7
  const int bh = idx & 31;
  const int qt = (r == 0) ? (31 - g) : (r == 1) ? (16 + g)
               : (r == 2) ? (15 - g) : g;     // balanced bijection
  const size_t qkbase = (size_t)bh * 4096 * 64;
  const size_t vbase = (size_t)bh * 64 * 4096;
  const int b = bh >> 4, hh = bh & 15;
  const int wrow0 = qt * 128 + w * 32;        // wave's first q-row
  const int nt = 2 * qt + 2;

  const int c0 = t, c1 = t + 256;
  const int kr0 = c0 >> 3, ks0 = ((c0 & 7) << 3) ^ ((kr0 & 7) << 3);
  const int kr1 = c1 >> 3, ks1 = ((c1 & 7) << 3) ^ ((kr1 & 7) << 3);

#define STAGE(bufi, jt)                                                             \
  do {                                                                              \
    gload16(Kb + qkbase + (size_t)((jt) * 64 + kr0) * 64 + ks0, &Kl[bufi][c0 * 8]); \
    gload16(Kb + qkbase + (size_t)((jt) * 64 + kr1) * 64 + ks1, &Kl[bufi][c1 * 8]); \
    gload16(VTb + vbase + (size_t)kr0 * 4096 + (jt) * 64 + ks0, &Vl[bufi][c0 * 8]); \
    gload16(VTb + vbase + (size_t)kr1 * 4096 + (jt) * 64 + ks1, &Vl[bufi][c1 * 8]); \
  } while (0)

  bf16x8 qf[2][2];
#pragma unroll
  for (int m = 0; m < 2; ++m)
#pragma unroll
    for (int kk = 0; kk < 2; ++kk)
      qf[m][kk] = *reinterpret_cast<const bf16x8*>(
          &Qb[qkbase + (size_t)(wrow0 + m * 16 + l15) * 64 + kk * 32 + l4 * 8]);

  // all-ones bf16 B-fragment for the row-sum MFMA
  u16x8 ones_u;
#pragma unroll
  for (int i = 0; i < 8; ++i) ones_u[i] = 0x3F80;  // bf16 1.0
  const bf16x8 onesf = __builtin_bit_cast(bf16x8, ones_u);

  f32x4 oacc[2][4] = {};
  f32x4 lacc[2] = {};

  STAGE(0, 0);
  asm volatile("s_waitcnt vmcnt(0)" ::: "memory");
  __builtin_amdgcn_s_barrier();

  for (int j = 0; j < nt; ++j) {
    const int cur = j & 1;
    if (j + 1 < nt) STAGE(cur ^ 1, j + 1);

    const int jk0 = j * 64;
    const bool active = (jk0 <= wrow0 + 31);
    const bool needmask = active && (jk0 + 63 > wrow0);

    if (active) {
#pragma unroll
      for (int h = 0; h < 2; ++h) {
        f32x4 sch[2][2] = {};
        __builtin_amdgcn_s_setprio(1);
#pragma unroll
        for (int nn = 0; nn < 2; ++nn) {
          int krow = (h * 2 + nn) * 16 + l15;
#pragma unroll
          for (int kk = 0; kk < 2; ++kk) {
            int kcol = (kk * 32 + l4 * 8) ^ ((krow & 7) << 3);
            bf16x8 kfr = *reinterpret_cast<const bf16x8*>(&Kl[cur][krow * 64 + kcol]);
#pragma unroll
            for (int m = 0; m < 2; ++m)
              sch[m][nn] = __builtin_amdgcn_mfma_f32_16x16x32_bf16(
                  kfr, qf[m][kk], sch[m][nn], 0, 0, 0);
          }
        }
        __builtin_amdgcn_s_setprio(0);

        bf16x8 pa[2];
#pragma unroll
        for (int m = 0; m < 2; ++m) {
#pragma unroll
          for (int nn = 0; nn < 2; ++nn)
#pragma unroll
            for (int r2 = 0; r2 < 4; ++r2)
              sch[m][nn][r2] = fast_exp2(sch[m][nn][r2]);
          if (needmask) {
            const int qg = wrow0 + m * 16 + l15;
#pragma unroll
            for (int nn = 0; nn < 2; ++nn) {
              const int kb = jk0 + (h * 2 + nn) * 16 + l4 * 4;
#pragma unroll
              for (int r2 = 0; r2 < 4; ++r2)
                if (kb + r2 > qg) sch[m][nn][r2] = 0.f;
            }
          }
          unsigned A0, A1, B0, B1;
          asm("v_cvt_pk_bf16_f32 %0, %1, %2"
              : "=v"(A0) : "v"(sch[m][0][0]), "v"(sch[m][0][1]));
          asm("v_cvt_pk_bf16_f32 %0, %1, %2"
              : "=v"(A1) : "v"(sch[m][0][2]), "v"(sch[m][0][3]));
          asm("v_cvt_pk_bf16_f32 %0, %1, %2"
              : "=v"(B0) : "v"(sch[m][1][0]), "v"(sch[m][1][1]));
          asm("v_cvt_pk_bf16_f32 %0, %1, %2"
              : "=v"(B1) : "v"(sch[m][1][2]), "v"(sch[m][1][3]));
          asm("v_permlane32_swap_b32 %0, %1" : "+v"(A0), "+v"(B0));
          asm("v_permlane16_swap_b32 %0, %1" : "+v"(A0), "+v"(B0));
          asm("v_permlane32_swap_b32 %0, %1" : "+v"(A1), "+v"(B1));
          asm("v_permlane16_swap_b32 %0, %1" : "+v"(A1), "+v"(B1));
          u32x4 pw;
          pw[0] = A0; pw[1] = A1; pw[2] = B0; pw[3] = B1;
          pa[m] = __builtin_bit_cast(bf16x8, pw);
        }

        __builtin_amdgcn_s_setprio(1);
        // row sums on the MFMA pipe (C row layout == oacc rows)
        lacc[0] = __builtin_amdgcn_mfma_f32_16x16x32_bf16(pa[0], onesf, lacc[0], 0, 0, 0);
        lacc[1] = __builtin_amdgcn_mfma_f32_16x16x32_bf16(pa[1], onesf, lacc[1], 0, 0, 0);
#pragma unroll
        for (int nn2 = 0; nn2 < 4; ++nn2) {
          int vr = nn2 * 16 + l15;
          int vc = (h * 32 + l4 * 8) ^ ((vr & 7) << 3);
          bf16x8 vf = *reinterpret_cast<const bf16x8*>(&Vl[cur][vr * 64 + vc]);
          oacc[0][nn2] = __builtin_amdgcn_mfma_f32_16x16x32_bf16(
              pa[0], vf, oacc[0][nn2], 0, 0, 0);
          oacc[1][nn2] = __builtin_amdgcn_mfma_f32_16x16x32_bf16(
              pa[1], vf, oacc[1][nn2], 0, 0, 0);
        }
        __builtin_amdgcn_s_setprio(0);
      }
    }

    asm volatile("s_waitcnt vmcnt(0)" ::: "memory");
    __builtin_amdgcn_s_barrier();
  }
#undef STAGE

  // epilogue: lacc[m][jj] holds the row sum for q = m*16 + l4*4 + jj
  // (identical row layout to oacc; every lane has its row's sum). No shuffles.
#pragma unroll
  for (int m = 0; m < 2; ++m)
#pragma unroll
    for (int jj = 0; jj < 4; ++jj) {
      float inv = 1.0f / lacc[m][jj];
      int srow = wrow0 + m * 16 + l4 * 4 + jj;
#pragma unroll
      for (int nn = 0; nn < 4; ++nn) {
        int col = hh * 64 + nn * 16 + l15;
        Ob[((size_t)(b * 4096 + srow)) * 1024 + col] =
            __builtin_bit_cast(unsigned short, (__bf16)(oacc[m][nn][jj] * inv));
      }
    }
}

// ---------------------------------------------------------------------------
extern "C" void kernel_launch(void* const* d_in, const int* in_sizes, int n_in,
                              void* d_out, int out_size, void* d_ws, size_t ws_size,
                              hipStream_t stream) {
  const float* x = (const float*)d_in[0];
  const float* Wqkv = (const float*)d_in[1];
  const float* bqkv = (const float*)d_in[2];
  const float* Wproj = (const float*)d_in[3];
  const float* bproj = (const float*)d_in[4];

  char* ws = (char*)d_ws;
  unsigned short* xb  = (unsigned short*)(ws);
  unsigned short* Wqb = (unsigned short*)(ws + 16777216);
  unsigned short* Wpb = (unsigned short*)(ws + 23068672);
  unsigned short* Qb  = (unsigned short*)(ws + 25165824);
  unsigned short* Kb  = (unsigned short*)(ws + 41943040);
  unsigned short* VTb = (unsigned short*)(ws + 58720256);
  unsigned short* Ob  = (unsigned short*)(ws + 75497472);

  k_cvt_bf16<<<dim3(8388608 / 8 / 256), dim3(256), 0, stream>>>(x, xb, 8388608 / 8);
  k_transcvt<<<dim3(3072 / 32, 1024 / 32), dim3(256), 0, stream>>>(Wqkv, Wqb, 1024, 3072);
  k_transcvt<<<dim3(1024 / 32, 1024 / 32), dim3(256), 0, stream>>>(Wproj, Wpb, 1024, 1024);
  k_gemm_qkv<<<dim3(3072 / 128, 8192 / 128), dim3(256), 0, stream>>>(xb, Wqb, bqkv, Qb, Kb, VTb);
  k_attn<<<dim3(1024), dim3(256), 0, stream>>>(Qb, Kb, VTb, Ob);
  k_gemm_proj<<<dim3(1024 / 128, 8192 / 128), dim3(256), 0, stream>>>(Ob, Wpb, bproj, (float*)d_out);
}

// Round 17
// 198.835 us; speedup vs baseline: 1.0087x; 1.0087x over previous
//
#include <hip/hip_runtime.h>
#include <stdint.h>

// ============================================================================
// MultiHeadAttentionFast: x[2,4096,1024] -> QKV gemm -> causal MHA -> proj
// B=2 S=4096 D=1024 H=16 DK=DV=64, QKV_OUT=3072. fp32 in/out, bf16 MFMA core.
// R17: GEMMs = R13 dbuf loop upgraded to RING-3 with counted vmcnt:
//      stage slot it+2 each iter; end-of-iter vmcnt(4) waits slot it+1
//      (issued a full iteration earlier -> latency covered by one extra
//      iteration of compute). One barrier/iter, plain 2D grid (no swizzle —
//      R11's FETCH-thrash lesson). attn = R16 (dual-pipe issue-bound, best).
// Workspace layout (bytes):
//   xb @0 (16MB) | WqkvT @16777216 (6MB) | WprojT @23068672 (2MB)
//   Q @25165824 | K @41943040 | V^T @58720256 | O @75497472 (16MB each)
// ============================================================================

typedef __bf16 bf16x8 __attribute__((ext_vector_type(8)));
typedef float f32x4 __attribute__((ext_vector_type(4)));
typedef unsigned short u16x8 __attribute__((ext_vector_type(8)));
typedef unsigned short u16x4 __attribute__((ext_vector_type(4)));
typedef unsigned int u32x4 __attribute__((ext_vector_type(4)));

__device__ __forceinline__ unsigned short f2bf(float f) {
  unsigned u = __builtin_bit_cast(unsigned, f);
  u += 0x7FFFu + ((u >> 16) & 1u);   // RNE
  return (unsigned short)(u >> 16);
}

__device__ __forceinline__ float fast_exp2(float x) {
#if __has_builtin(__builtin_amdgcn_exp2f)
  return __builtin_amdgcn_exp2f(x);
#else
  return exp2f(x);
#endif
}

// global -> LDS direct, 16B per lane (wave-uniform LDS base + lane*16).
__device__ __forceinline__ void gload16(const void* g, void* l) {
  __builtin_amdgcn_global_load_lds(
      (__attribute__((address_space(1))) unsigned int*)(uintptr_t)g,
      (__attribute__((address_space(3))) unsigned int*)(unsigned int)(uintptr_t)l,
      16, 0, 0);
}

// ---------------------------------------------------------------------------
__global__ void k_cvt_bf16(const float* __restrict__ in,
                           unsigned short* __restrict__ out, int n8) {
  int i = blockIdx.x * blockDim.x + threadIdx.x;
  if (i >= n8) return;
  const float4* p = reinterpret_cast<const float4*>(in) + (size_t)i * 2;
  float4 a = p[0], b = p[1];
  u16x8 o;
  o[0] = f2bf(a.x); o[1] = f2bf(a.y); o[2] = f2bf(a.z); o[3] = f2bf(a.w);
  o[4] = f2bf(b.x); o[5] = f2bf(b.y); o[6] = f2bf(b.z); o[7] = f2bf(b.w);
  *(reinterpret_cast<u16x8*>(out) + i) = o;
}

__global__ void k_transcvt(const float* __restrict__ in,
                           unsigned short* __restrict__ out, int K, int N) {
  __shared__ float tile[32][33];
  int tk0 = blockIdx.y << 5, tn0 = blockIdx.x << 5;
  int t = threadIdx.x;
  int r = t >> 3, c4 = (t & 7) << 2;
  float4 v = *reinterpret_cast<const float4*>(&in[(size_t)(tk0 + r) * N + tn0 + c4]);
  tile[r][c4 + 0] = v.x; tile[r][c4 + 1] = v.y;
  tile[r][c4 + 2] = v.z; tile[r][c4 + 3] = v.w;
  __syncthreads();
  u16x4 o;
  o[0] = f2bf(tile[c4 + 0][r]); o[1] = f2bf(tile[c4 + 1][r]);
  o[2] = f2bf(tile[c4 + 2][r]); o[3] = f2bf(tile[c4 + 3][r]);
  *reinterpret_cast<u16x4*>(&out[(size_t)(tn0 + r) * K + tk0 + c4]) = o;
}

// ---------------------------------------------------------------------------
// RING-3 128x128x(K=1024) bf16 GEMM core, BK=32, 4 waves (2x2).
// Iter it: stage slot (it+2)%3 (4 gload16), 8 ds_read_b128 from slot it%3,
// 16 MFMA, vmcnt(4) [slot it+1 landed; its loads were issued in iter it-1 ->
// a full iteration of latency cover], ONE barrier.
// WAR: slot it%3 is re-staged in iter it+1, protected by iter-it barrier.
__device__ __forceinline__ void gemm_core_r3(
    const unsigned short* __restrict__ A, const unsigned short* __restrict__ Bt,
    unsigned short (*Al)[128 * 32], unsigned short (*Bl)[128 * 32],
    int m0, int n0, f32x4 acc[4][4]) {
  const int t = threadIdx.x;
  const int lane = t & 63;
  const int w = t >> 6;
  const int wr = w >> 1, wc = w & 1;
  const int l15 = lane & 15, l4 = lane >> 4;

  const int c0 = t, c1 = t + 256;
  const int r0 = c0 >> 2, s0 = ((c0 & 3) << 3) ^ (((r0 >> 1) & 3) << 3);
  const int r1 = c1 >> 2, s1 = ((c1 & 3) << 3) ^ (((r1 >> 1) & 3) << 3);
  const size_t ga0 = (size_t)(m0 + r0) * 1024 + s0;
  const size_t ga1 = (size_t)(m0 + r1) * 1024 + s1;
  const size_t gb0 = (size_t)(n0 + r0) * 1024 + s0;
  const size_t gb1 = (size_t)(n0 + r1) * 1024 + s1;

  int aidx[4], bidx[4];
#pragma unroll
  for (int m = 0; m < 4; ++m) {
    int row = wr * 64 + m * 16 + l15;
    aidx[m] = row * 32 + ((l4 * 8) ^ (((row >> 1) & 3) << 3));
    row = wc * 64 + m * 16 + l15;
    bidx[m] = row * 32 + ((l4 * 8) ^ (((row >> 1) & 3) << 3));
  }

#define GSTAGE(sl, kofs)                                     \
  do {                                                       \
    gload16(A + ga0 + (kofs), Al[sl] + c0 * 8);              \
    gload16(A + ga1 + (kofs), Al[sl] + c1 * 8);              \
    gload16(Bt + gb0 + (kofs), Bl[sl] + c0 * 8);             \
    gload16(Bt + gb1 + (kofs), Bl[sl] + c1 * 8);             \
  } while (0)

  // prologue: slots 0 (k=0) and 1 (k=32) in flight; wait slot 0; sync.
  GSTAGE(0, 0);
  GSTAGE(1, 32);
  asm volatile("s_waitcnt vmcnt(4)" ::: "memory");
  __builtin_amdgcn_s_barrier();

  int cur = 0;
#pragma unroll 1
  for (int it = 0; it < 32; ++it) {
    int nxt = cur + 1; if (nxt == 3) nxt = 0;
    int pre = nxt + 1; if (pre == 3) pre = 0;     // slot for it+2
    if (it + 2 < 32) GSTAGE(pre, (it + 2) * 32);  // flies for a full iter
    bf16x8 af[4], bfr[4];
#pragma unroll
    for (int m = 0; m < 4; ++m)
      af[m] = *reinterpret_cast<const bf16x8*>(Al[cur] + aidx[m]);
#pragma unroll
    for (int n = 0; n < 4; ++n)
      bfr[n] = *reinterpret_cast<const bf16x8*>(Bl[cur] + bidx[n]);
    __builtin_amdgcn_s_setprio(1);
#pragma unroll
    for (int m = 0; m < 4; ++m)
#pragma unroll
      for (int n = 0; n < 4; ++n)
        acc[m][n] = __builtin_amdgcn_mfma_f32_16x16x32_bf16(af[m], bfr[n],
                                                            acc[m][n], 0, 0, 0);
    __builtin_amdgcn_s_setprio(0);
    if (it + 2 < 32) {
      asm volatile("s_waitcnt vmcnt(4)" ::: "memory");   // slot it+1 landed
    } else if (it + 1 < 32) {
      asm volatile("s_waitcnt vmcnt(0)" ::: "memory");   // final slot landed
    }
    if (it + 1 < 32) __builtin_amdgcn_s_barrier();
    cur = nxt;
  }
#undef GSTAGE
}

__global__ __launch_bounds__(256) void k_gemm_qkv(
    const unsigned short* __restrict__ A, const unsigned short* __restrict__ Bt,
    const float* __restrict__ bias, unsigned short* __restrict__ Qb,
    unsigned short* __restrict__ Kb, unsigned short* __restrict__ VTb) {
  __shared__ unsigned short Al[3][128 * 32];
  __shared__ unsigned short Bl[3][128 * 32];
  const int lane = threadIdx.x & 63, w = threadIdx.x >> 6;
  const int wr = w >> 1, wc = w & 1;
  const int l15 = lane & 15, l4 = lane >> 4;
  const int m0 = blockIdx.y << 7, n0 = blockIdx.x << 7;
  const float C1 = 0.18033688011112043f;   // 0.125 * log2(e), folded into Q

  f32x4 acc[4][4] = {};
  gemm_core_r3(A, Bt, Al, Bl, m0, n0, acc);

  float bi[4];
#pragma unroll
  for (int n = 0; n < 4; ++n) bi[n] = bias[n0 + wc * 64 + n * 16 + l15];

  if (n0 < 2048) {          // Q or K region: coalesced 2B stores (d-contig)
#pragma unroll
    for (int m = 0; m < 4; ++m)
#pragma unroll
      for (int n = 0; n < 4; ++n)
#pragma unroll
        for (int j = 0; j < 4; ++j) {
          int row = m0 + wr * 64 + m * 16 + l4 * 4 + j;
          int col = n0 + wc * 64 + n * 16 + l15;
          float v = acc[m][n][j] + bi[n];
          int b = row >> 12, s = row & 4095;
          if (col < 1024) {
            int hh = col >> 6, d = col & 63;
            Qb[((size_t)(b * 16 + hh) * 4096 + s) * 64 + d] = f2bf(v * C1);
          } else {
            int cc = col - 1024; int hh = cc >> 6, d = cc & 63;
            Kb[((size_t)(b * 16 + hh) * 4096 + s) * 64 + d] = f2bf(v);
          }
        }
  } else {                  // V region -> V^T: 4 consecutive s, packed 8B
#pragma unroll
    for (int m = 0; m < 4; ++m)
#pragma unroll
      for (int n = 0; n < 4; ++n) {
        int row0 = m0 + wr * 64 + m * 16 + l4 * 4;
        int cc = n0 - 2048 + wc * 64 + n * 16 + l15;
        int b = row0 >> 12, s0 = row0 & 4095;
        int hh = cc >> 6, d = cc & 63;
        u16x4 pk;
#pragma unroll
        for (int j = 0; j < 4; ++j) pk[j] = f2bf(acc[m][n][j] + bi[n]);
        *reinterpret_cast<u16x4*>(
            &VTb[((size_t)(b * 16 + hh) * 64 + d) * 4096 + s0]) = pk;
      }
  }
}

__global__ __launch_bounds__(256) void k_gemm_proj(
    const unsigned short* __restrict__ A, const unsigned short* __restrict__ Bt,
    const float* __restrict__ bias, float* __restrict__ out) {
  __shared__ unsigned short Al[3][128 * 32];
  __shared__ unsigned short Bl[3][128 * 32];
  const int lane = threadIdx.x & 63, w = threadIdx.x >> 6;
  const int wr = w >> 1, wc = w & 1;
  const int l15 = lane & 15, l4 = lane >> 4;
  const int m0 = blockIdx.y << 7, n0 = blockIdx.x << 7;

  f32x4 acc[4][4] = {};
  gemm_core_r3(A, Bt, Al, Bl, m0, n0, acc);

#pragma unroll
  for (int m = 0; m < 4; ++m) {
#pragma unroll
    for (int n = 0; n < 4; ++n) {
#pragma unroll
      for (int j = 0; j < 4; ++j) {
        int row = m0 + wr * 64 + m * 16 + l4 * 4 + j;
        int col = n0 + wc * 64 + n * 16 + l15;
        out[(size_t)row * 1024 + col] = acc[m][n][j] + bias[col];
      }
    }
  }
}

// ---------------------------------------------------------------------------
// Flash attention (R16, unchanged). 1024 blocks (balanced qt bijection),
// 4 waves x 32 q-rows. Swapped QK^T (Q pre-scaled); P in registers via
// cvt_pk + permlane; row sums via ones-column MFMA (epilogue shuffle-free).
__global__ __launch_bounds__(256, 4) void k_attn(
    const unsigned short* __restrict__ Qb, const unsigned short* __restrict__ Kb,
    const unsigned short* __restrict__ VTb, unsigned short* __restrict__ Ob) {
  __shared__ unsigned short Kl[2][64 * 64];
  __shared__ unsigned short Vl[2][64 * 64];
  const int t = threadIdx.x;
  const int lane = t & 63, w = t >> 6;
  const int l15 = lane & 15, l4 = lane >> 4;
  const int idx = blockIdx.x;
  const int r = idx >> 8;                     // round 0..3
  const int g = (idx >> 5) & 7;               // group 0..7
  const int bh = idx & 31;
  const int qt = (r == 0) ? (31 - g) : (r == 1) ? (16 + g)
               : (r == 2) ? (15 - g) : g;     // balanced bijection
  const size_t qkbase = (size_t)bh * 4096 * 64;
  const size_t vbase = (size_t)bh * 64 * 4096;
  const int b = bh >> 4, hh = bh & 15;
  const int wrow0 = qt * 128 + w * 32;        // wave's first q-row
  const int nt = 2 * qt + 2;

  const int c0 = t, c1 = t + 256;
  const int kr0 = c0 >> 3, ks0 = ((c0 & 7) << 3) ^ ((kr0 & 7) << 3);
  const int kr1 = c1 >> 3, ks1 = ((c1 & 7) << 3) ^ ((kr1 & 7) << 3);

#define STAGE(bufi, jt)                                                             \
  do {                                                                              \
    gload16(Kb + qkbase + (size_t)((jt) * 64 + kr0) * 64 + ks0, &Kl[bufi][c0 * 8]); \
    gload16(Kb + qkbase + (size_t)((jt) * 64 + kr1) * 64 + ks1, &Kl[bufi][c1 * 8]); \
    gload16(VTb + vbase + (size_t)kr0 * 4096 + (jt) * 64 + ks0, &Vl[bufi][c0 * 8]); \
    gload16(VTb + vbase + (size_t)kr1 * 4096 + (jt) * 64 + ks1, &Vl[bufi][c1 * 8]); \
  } while (0)

  bf16x8 qf[2][2];
#pragma unroll
  for (int m = 0; m < 2; ++m)
#pragma unroll
    for (int kk = 0; kk < 2; ++kk)
      qf[m][kk] = *reinterpret_cast<const bf16x8*>(
          &Qb[qkbase + (size_t)(wrow0 + m * 16 + l15) * 64 + kk * 32 + l4 * 8]);

  // all-ones bf16 B-fragment for the row-sum MFMA
  u16x8 ones_u;
#pragma unroll
  for (int i = 0; i < 8; ++i) ones_u[i] = 0x3F80;  // bf16 1.0
  const bf16x8 onesf = __builtin_bit_cast(bf16x8, ones_u);

  f32x4 oacc[2][4] = {};
  f32x4 lacc[2] = {};

  STAGE(0, 0);
  asm volatile("s_waitcnt vmcnt(0)" ::: "memory");
  __builtin_amdgcn_s_barrier();

  for (int j = 0; j < nt; ++j) {
    const int cur = j & 1;
    if (j + 1 < nt) STAGE(cur ^ 1, j + 1);

    const int jk0 = j * 64;
    const bool active = (jk0 <= wrow0 + 31);
    const bool needmask = active && (jk0 + 63 > wrow0);

    if (active) {
#pragma unroll
      for (int h = 0; h < 2; ++h) {
        f32x4 sch[2][2] = {};
        __builtin_amdgcn_s_setprio(1);
#pragma unroll
        for (int nn = 0; nn < 2; ++nn) {
          int krow = (h * 2 + nn) * 16 + l15;
#pragma unroll
          for (int kk = 0; kk < 2; ++kk) {
            int kcol = (kk * 32 + l4 * 8) ^ ((krow & 7) << 3);
            bf16x8 kfr = *reinterpret_cast<const bf16x8*>(&Kl[cur][krow * 64 + kcol]);
#pragma unroll
            for (int m = 0; m < 2; ++m)
              sch[m][nn] = __builtin_amdgcn_mfma_f32_16x16x32_bf16(
                  kfr, qf[m][kk], sch[m][nn], 0, 0, 0);
          }
        }
        __builtin_amdgcn_s_setprio(0);

        bf16x8 pa[2];
#pragma unroll
        for (int m = 0; m < 2; ++m) {
#pragma unroll
          for (int nn = 0; nn < 2; ++nn)
#pragma unroll
            for (int r2 = 0; r2 < 4; ++r2)
              sch[m][nn][r2] = fast_exp2(sch[m][nn][r2]);
          if (needmask) {
            const int qg = wrow0 + m * 16 + l15;
#pragma unroll
            for (int nn = 0; nn < 2; ++nn) {
              const int kb = jk0 + (h * 2 + nn) * 16 + l4 * 4;
#pragma unroll
              for (int r2 = 0; r2 < 4; ++r2)
                if (kb + r2 > qg) sch[m][nn][r2] = 0.f;
            }
          }
          unsigned A0, A1, B0, B1;
          asm("v_cvt_pk_bf16_f32 %0, %1, %2"
              : "=v"(A0) : "v"(sch[m][0][0]), "v"(sch[m][0][1]));
          asm("v_cvt_pk_bf16_f32 %0, %1, %2"
              : "=v"(A1) : "v"(sch[m][0][2]), "v"(sch[m][0][3]));
          asm("v_cvt_pk_bf16_f32 %0, %1, %2"
              : "=v"(B0) : "v"(sch[m][1][0]), "v"(sch[m][1][1]));
          asm("v_cvt_pk_bf16_f32 %0, %1, %2"
              : "=v"(B1) : "v"(sch[m][1][2]), "v"(sch[m][1][3]));
          asm("v_permlane32_swap_b32 %0, %1" : "+v"(A0), "+v"(B0));
          asm("v_permlane16_swap_b32 %0, %1" : "+v"(A0), "+v"(B0));
          asm("v_permlane32_swap_b32 %0, %1" : "+v"(A1), "+v"(B1));
          asm("v_permlane16_swap_b32 %0, %1" : "+v"(A1), "+v"(B1));
          u32x4 pw;
          pw[0] = A0; pw[1] = A1; pw[2] = B0; pw[3] = B1;
          pa[m] = __builtin_bit_cast(bf16x8, pw);
        }

        __builtin_amdgcn_s_setprio(1);
        // row sums on the MFMA pipe (C row layout == oacc rows)
        lacc[0] = __builtin_amdgcn_mfma_f32_16x16x32_bf16(pa[0], onesf, lacc[0], 0, 0, 0);
        lacc[1] = __builtin_amdgcn_mfma_f32_16x16x32_bf16(pa[1], onesf, lacc[1], 0, 0, 0);
#pragma unroll
        for (int nn2 = 0; nn2 < 4; ++nn2) {
          int vr = nn2 * 16 + l15;
          int vc = (h * 32 + l4 * 8) ^ ((vr & 7) << 3);
          bf16x8 vf = *reinterpret_cast<const bf16x8*>(&Vl[cur][vr * 64 + vc]);
          oacc[0][nn2] = __builtin_amdgcn_mfma_f32_16x16x32_bf16(
              pa[0], vf, oacc[0][nn2], 0, 0, 0);
          oacc[1][nn2] = __builtin_amdgcn_mfma_f32_16x16x32_bf16(
              pa[1], vf, oacc[1][nn2], 0, 0, 0);
        }
        __builtin_amdgcn_s_setprio(0);
      }
    }

    asm volatile("s_waitcnt vmcnt(0)" ::: "memory");
    __builtin_amdgcn_s_barrier();
  }
#undef STAGE

  // epilogue: lacc[m][jj] holds the row sum for q = m*16 + l4*4 + jj.
#pragma unroll
  for (int m = 0; m < 2; ++m)
#pragma unroll
    for (int jj = 0; jj < 4; ++jj) {
      float inv = 1.0f / lacc[m][jj];
      int srow = wrow0 + m * 16 + l4 * 4 + jj;
#pragma unroll
      for (int nn = 0; nn < 4; ++nn) {
        int col = hh * 64 + nn * 16 + l15;
        Ob[((size_t)(b * 4096 + srow)) * 1024 + col] =
            __builtin_bit_cast(unsigned short, (__bf16)(oacc[m][nn][jj] * inv));
      }
    }
}

// ---------------------------------------------------------------------------
extern "C" void kernel_launch(void* const* d_in, const int* in_sizes, int n_in,
                              void* d_out, int out_size, void* d_ws, size_t ws_size,
                              hipStream_t stream) {
  const float* x = (const float*)d_in[0];
  const float* Wqkv = (const float*)d_in[1];
  const float* bqkv = (const float*)d_in[2];
  const float* Wproj = (const float*)d_in[3];
  const float* bproj = (const float*)d_in[4];

  char* ws = (char*)d_ws;
  unsigned short* xb  = (unsigned short*)(ws);
  unsigned short* Wqb = (unsigned short*)(ws + 16777216);
  unsigned short* Wpb = (unsigned short*)(ws + 23068672);
  unsigned short* Qb  = (unsigned short*)(ws + 25165824);
  unsigned short* Kb  = (unsigned short*)(ws + 41943040);
  unsigned short* VTb = (unsigned short*)(ws + 58720256);
  unsigned short* Ob  = (unsigned short*)(ws + 75497472);

  k_cvt_bf16<<<dim3(8388608 / 8 / 256), dim3(256), 0, stream>>>(x, xb, 8388608 / 8);
  k_transcvt<<<dim3(3072 / 32, 1024 / 32), dim3(256), 0, stream>>>(Wqkv, Wqb, 1024, 3072);
  k_transcvt<<<dim3(1024 / 32, 1024 / 32), dim3(256), 0, stream>>>(Wproj, Wpb, 1024, 1024);
  k_gemm_qkv<<<dim3(3072 / 128, 8192 / 128), dim3(256), 0, stream>>>(xb, Wqb, bqkv, Qb, Kb, VTb);
  k_attn<<<dim3(1024), dim3(256), 0, stream>>>(Qb, Kb, VTb, Ob);
  k_gemm_proj<<<dim3(1024 / 128, 8192 / 128), dim3(256), 0, stream>>>(Ob, Wpb, bproj, (float*)d_out);
}